// Round 10
// baseline (32.267 us; speedup 1.0000x reference)
//
#include <hip/hip_runtime.h>

// Problem constants (fixed by the reference setup)
#define NN   32
#define CCH  2
#define PP   (512*512)       // 262144 pixels per image plane
#define RR   (NN*CCH)        // 64 rows
#define NB   256             // distance-quantization buckets over [0,1]
#define BPI  64              // hist blocks per image
#define GRID (NN*BPI)        // 2048 blocks -> 8/CU, all co-resident @32 waves
#define SPAN (PP/BPI)        // 4096 px per block
#define HT   256             // threads per hist block (4 waves)
#define GRAN (HT*4)          // 1024 px per granule (4 px/thread)
#define NG   (SPAN/GRAN)     // 4 granules, register-prefetched
#define ST   256             // threads per scan block == NB

static_assert(ST == NB, "scan assumes one bucket per thread");
static_assert(NG == 4, "manual prefetch unroll below assumes 4 granules");
static_assert(SPAN < 65536, "packed 16-bit cnt would overflow");
static_assert(HT == NB, "partial writeout shape");
static_assert(RR <= 64, "final reduce assumes one wave");

__device__ __forceinline__ double iou_f(double msum, unsigned k, unsigned cs) {
    if (k == 0u) return 0.0;              // "iou before position 1" is 0
    if (msum == 0.0) return 1.0;          // no ones: inter=0, union=k -> iou=1
    const double dk = (double)k, dcs = (double)cs;
    return 1.0 - (msum - dcs) / (msum + dk - dcs);
}

struct Batch {                            // one granule's data for one thread
    float4 a;                             // ch0 x, 4 px
    float4 b;                             // ch1 x, 4 px
    int4   t;                             // targets, 4 px
};

// Kernel 1: max-occupancy streaming hist. 256-thr blocks, VGPR<=64 via
// __launch_bounds__(256,8) -> 32 waves/CU; 2048 blocks all co-resident.
// Depth-1 register prefetch keeps HBM loads in flight during the LDS-atomic
// phases. Packed LDS u32 (cnt<<16|ones) per channel, one atomic per
// (pixel,channel). Pure integer -> bit-deterministic.
__global__ __launch_bounds__(HT, 8) void hist_kernel(
        const float* __restrict__ x, const int* __restrict__ tgt,
        unsigned* __restrict__ g_part, unsigned* __restrict__ g_pos,
        unsigned* __restrict__ g_ticket)
{
    __shared__ unsigned s_h0[NB];            // 1 KB
    __shared__ unsigned s_h1[NB];            // 1 KB
    __shared__ unsigned s_posr[HT/64][2];

    const int nb  = blockIdx.x;              // 0 .. GRID-1
    const int n   = nb / BPI, blk = nb % BPI;
    const int tid = threadIdx.x;

    if (nb == 0 && tid == 0) *g_ticket = 0u; // ordered by kernel boundary

    s_h0[tid] = 0u; s_h1[tid] = 0u;          // HT == NB
    __syncthreads();

    const float* x0 = x   + ((size_t)(n*CCH + 0))*PP + (size_t)blk*SPAN;
    const float* x1 = x   + ((size_t)(n*CCH + 1))*PP + (size_t)blk*SPAN;
    const int*   tr = tgt + (size_t)n*PP            + (size_t)blk*SPAN;

    unsigned pos0 = 0, pos1 = 0;

    auto load = [&](int g) -> Batch {
        Batch b;
        const int p = g*GRAN + tid*4;
        b.a = *reinterpret_cast<const float4*>(x0 + p);
        b.b = *reinterpret_cast<const float4*>(x1 + p);
        b.t = *reinterpret_cast<const int4*>(tr + p);
        return b;
    };
    auto proc = [&](const Batch& b) {
        const float xs0[4] = {b.a.x, b.a.y, b.a.z, b.a.w};
        const float xs1[4] = {b.b.x, b.b.y, b.b.z, b.b.w};
        const int   ts [4] = {b.t.x, b.t.y, b.t.z, b.t.w};
        #pragma unroll
        for (int j = 0; j < 4; ++j) {
            const bool z = (ts[j] == 0);                 // targets are {0,1}
            const float d0 = z ? (1.0f - xs0[j]) : xs0[j];
            const float d1 = z ? xs1[j] : (1.0f - xs1[j]);
            int k0 = (int)(d0 * (float)NB); k0 = k0 > NB-1 ? NB-1 : k0;
            int k1 = (int)(d1 * (float)NB); k1 = k1 > NB-1 ? NB-1 : k1;
            atomicAdd(&s_h0[k0], 0x10000u | (z ? 1u : 0u));
            atomicAdd(&s_h1[k1], 0x10000u | (z ? 0u : 1u));
            pos0 += (xs0[j] > 0.25f) ? 1u : 0u;
            pos1 += (xs1[j] > 0.25f) ? 1u : 0u;
        }
    };

    // depth-1 prefetch, fully static (no runtime-indexed register arrays)
    Batch c0 = load(0);
    Batch c1 = load(1);      // in flight while proc(c0) runs
    proc(c0);
    Batch c2 = load(2);
    proc(c1);
    Batch c3 = load(3);
    proc(c2);
    proc(c3);

    for (int off = 32; off; off >>= 1) {
        pos0 += __shfl_down(pos0, off);
        pos1 += __shfl_down(pos1, off);
    }
    if ((tid & 63) == 0) { s_posr[tid>>6][0] = pos0; s_posr[tid>>6][1] = pos1; }
    __syncthreads();                       // also completes LDS hist atomics

    if (tid == 0) {
        unsigned q0 = 0, q1 = 0;
        #pragma unroll
        for (int w = 0; w < HT/64; ++w) { q0 += s_posr[w][0]; q1 += s_posr[w][1]; }
        g_pos[nb*CCH + 0] = q0; g_pos[nb*CCH + 1] = q1;
    }
    // one partial u32 per (ch,bucket) per block; HT == NB -> two stores
    g_part[(size_t)nb*(CCH*NB) + tid]      = s_h0[tid];
    g_part[(size_t)nb*(CCH*NB) + NB + tid] = s_h1[tid];
}

// Kernel 2: one block per row (n,c). Thread tid owns scan position tid
// (bucket NB-1-tid): merge the BPI block-partials in registers, wave-shuffle
// u64 scan, accumulate d_mid * (iou_incl - iou_excl) in double.
// Last block (ticket) reduces the 64 rows to the final scalar.
__global__ __launch_bounds__(ST) void scan_kernel(
        const unsigned* __restrict__ g_part, const unsigned* __restrict__ g_pos,
        float* __restrict__ g_row, float* __restrict__ g_valid,
        unsigned* __restrict__ g_ticket, float* __restrict__ out)
{
    __shared__ unsigned long long s_wsum[ST/64];
    __shared__ double   s_red[ST/64];
    __shared__ unsigned s_flag;

    const int r = blockIdx.x;
    const int n = r / CCH, c = r % CCH;
    const int tid = threadIdx.x, lane = tid & 63, wv = tid >> 6;

    const int bk = NB-1 - tid;             // descending distance, position=tid
    unsigned lc = 0, lo = 0;
    #pragma unroll 8
    for (int b = 0; b < BPI; ++b) {
        const unsigned v = g_part[(size_t)(n*BPI + b)*(CCH*NB) + c*NB + bk];
        lc += v >> 16; lo += v & 0xffffu;
    }

    // intra-wave inclusive scan of packed (cnt<<32 | ones)
    const unsigned long long v =
        ((unsigned long long)lc << 32) | (unsigned long long)lo;
    unsigned long long s = v;
    #pragma unroll
    for (int off = 1; off < 64; off <<= 1) {
        const unsigned long long t = __shfl_up(s, off, 64);
        if (lane >= off) s += t;
    }
    if (lane == 63) s_wsum[wv] = s;
    __syncthreads();
    unsigned long long woff = 0, tot = 0;
    #pragma unroll
    for (int w = 0; w < ST/64; ++w) {
        const unsigned long long u = s_wsum[w];
        tot += u;
        if (w < wv) woff += u;
    }
    const unsigned long long excl = s + woff - v;
    const unsigned msum = (unsigned)(tot & 0xffffffffu);
    const unsigned k  = (unsigned)(excl >> 32);
    const unsigned cs = (unsigned)(excl & 0xffffffffu);

    double acc = 0.0;
    if (lc) {
        const double dmsum = (double)msum;
        const double ip  = iou_f(dmsum, k, cs);
        const double in_ = iou_f(dmsum, k + lc, cs + lo);
        acc = (((double)bk + 0.5) * (1.0/(double)NB)) * (in_ - ip);
    }
    for (int off = 32; off; off >>= 1) acc += __shfl_down(acc, off);
    if (lane == 0) s_red[wv] = acc;
    __syncthreads();
    if (tid == 0) {
        double t = 0.0;
        #pragma unroll
        for (int w = 0; w < ST/64; ++w) t += s_red[w];
        unsigned pos = 0;
        for (int b = 0; b < BPI; ++b) pos += g_pos[(n*BPI + b)*CCH + c];
        const bool valid = !(msum == 0u && pos == 0u);
        const double W[CCH] = {1.428, 40.097};
        g_row[r]   = valid ? (float)(t * W[c]) : 0.f;
        g_valid[r] = valid ? 1.f : 0.f;
        __threadfence();                   // publish row result device-wide
        s_flag = atomicAdd(g_ticket, 1u);  // device-scope by default
    }
    __syncthreads();

    if (s_flag == RR - 1) {                // last block reduces all rows
        __threadfence();
        if (tid < 64) {
            const volatile float* vr = g_row;
            const volatile float* vv = g_valid;
            double t  = (tid < RR) ? (double)vr[tid] : 0.0;
            double vl = (tid < RR) ? (double)vv[tid] : 0.0;
            for (int off = 32; off; off >>= 1) {
                t  += __shfl_down(t, off);
                vl += __shfl_down(vl, off);
            }
            if (tid == 0) out[0] = (float)(t / (double)NN / vl);
        }
    }
}

extern "C" void kernel_launch(void* const* d_in, const int* in_sizes, int n_in,
                              void* d_out, int out_size, void* d_ws, size_t ws_size,
                              hipStream_t stream) {
    const float* x   = (const float*)d_in[0];
    const int*   tgt = (const int*)d_in[1];
    float* out = (float*)d_out;

    // workspace (~4.2 MB): every word written before read -> no memset
    const size_t SZP = (size_t)GRID * CCH * NB;          // partials (u32)
    unsigned* g_part  = (unsigned*)d_ws;
    unsigned* g_pos   = g_part + SZP;                    // GRID*2 u32
    float*    g_row   = (float*)(g_pos + GRID*CCH);      // RR floats
    float*    g_valid = g_row + RR;                      // RR floats
    unsigned* g_ticket = (unsigned*)(g_valid + RR);      // 1 u32

    hist_kernel<<<GRID, HT, 0, stream>>>(x, tgt, g_part, g_pos, g_ticket);
    scan_kernel<<<RR, ST, 0, stream>>>(g_part, g_pos, g_row, g_valid, g_ticket, out);
}

// Round 11
// 27.744 us; speedup vs baseline: 1.1630x; 1.1630x over previous
//
#include <hip/hip_runtime.h>

// Problem constants (fixed by the reference setup)
#define NN   32
#define CCH  2
#define PP   (512*512)       // 262144 pixels per image plane
#define RR   (NN*CCH)        // 64 rows
#define NB   256             // distance-quantization buckets over [0,1]
#define BPI  16              // hist blocks per image
#define GRID (NN*BPI)        // 512 blocks -> 2/CU, all co-resident
#define SPAN (PP/BPI)        // 16384 px per block
#define HT   512             // threads per hist block
#define GRAN (HT*8)          // 4096 px per granule (8 px/thread)
#define NG   (SPAN/GRAN)     // 4 granules, register-prefetched
#define ST   256             // threads per scan block == NB

static_assert(ST == NB, "scan assumes one bucket per thread");
static_assert(HT == 2*NB, "partial writeout shape");
static_assert(NG == 4, "manual prefetch unroll below assumes 4 granules");
static_assert(SPAN < 65536, "packed 16-bit cnt would overflow");
static_assert(RR <= 64, "final reduce assumes one wave");

__device__ __forceinline__ double iou_f(double msum, unsigned k, unsigned cs) {
    if (k == 0u) return 0.0;              // "iou before position 1" is 0
    if (msum == 0.0) return 1.0;          // no ones: inter=0, union=k -> iou=1
    const double dk = (double)k, dcs = (double)cs;
    return 1.0 - (msum - dcs) / (msum + dk - dcs);
}

struct Batch {                            // one granule's data for one thread
    float4 a0, a1;                        // ch0 x, 8 px
    float4 b0, b1;                        // ch1 x, 8 px
    int4   t0, t1;                        // targets, 8 px
};

// Kernel 1: persistent-style hist. Each block owns a contiguous 16384-px
// span of image n; 4 granules with depth-1 register prefetch so HBM loads
// stay in flight during the LDS-atomic phases (no fill/drain bubbles —
// whole grid co-resident). Packed LDS u32 (cnt<<16|ones), one atomic per
// (pixel,channel). Pure integer -> bit-deterministic.
__global__ __launch_bounds__(HT, 4) void hist_kernel(
        const float* __restrict__ x, const int* __restrict__ tgt,
        unsigned* __restrict__ g_part, unsigned* __restrict__ g_pos,
        unsigned* __restrict__ g_ticket)
{
    __shared__ unsigned s_h0[NB];            // 1 KB
    __shared__ unsigned s_h1[NB];            // 1 KB
    __shared__ unsigned s_posr[HT/64][2];

    const int nb  = blockIdx.x;              // 0 .. GRID-1
    const int n   = nb / BPI, blk = nb % BPI;
    const int tid = threadIdx.x;

    if (nb == 0 && tid == 0) *g_ticket = 0u; // ordered by kernel boundary

    if (tid < NB) s_h0[tid] = 0u; else s_h1[tid - NB] = 0u;
    __syncthreads();

    const float* x0 = x   + ((size_t)(n*CCH + 0))*PP + (size_t)blk*SPAN;
    const float* x1 = x   + ((size_t)(n*CCH + 1))*PP + (size_t)blk*SPAN;
    const int*   tr = tgt + (size_t)n*PP            + (size_t)blk*SPAN;

    unsigned pos0 = 0, pos1 = 0;

    auto load = [&](int g) -> Batch {
        Batch b;
        const int p = g*GRAN + tid*8;
        b.a0 = *reinterpret_cast<const float4*>(x0 + p);
        b.a1 = *reinterpret_cast<const float4*>(x0 + p + 4);
        b.b0 = *reinterpret_cast<const float4*>(x1 + p);
        b.b1 = *reinterpret_cast<const float4*>(x1 + p + 4);
        b.t0 = *reinterpret_cast<const int4*>(tr + p);
        b.t1 = *reinterpret_cast<const int4*>(tr + p + 4);
        return b;
    };
    auto proc = [&](const Batch& b) {
        const float xs0[8] = {b.a0.x,b.a0.y,b.a0.z,b.a0.w, b.a1.x,b.a1.y,b.a1.z,b.a1.w};
        const float xs1[8] = {b.b0.x,b.b0.y,b.b0.z,b.b0.w, b.b1.x,b.b1.y,b.b1.z,b.b1.w};
        const int   ts [8] = {b.t0.x,b.t0.y,b.t0.z,b.t0.w, b.t1.x,b.t1.y,b.t1.z,b.t1.w};
        #pragma unroll
        for (int j = 0; j < 8; ++j) {
            const bool z = (ts[j] == 0);                 // targets are {0,1}
            const float d0 = z ? (1.0f - xs0[j]) : xs0[j];
            const float d1 = z ? xs1[j] : (1.0f - xs1[j]);
            int k0 = (int)(d0 * (float)NB); k0 = k0 > NB-1 ? NB-1 : k0;
            int k1 = (int)(d1 * (float)NB); k1 = k1 > NB-1 ? NB-1 : k1;
            atomicAdd(&s_h0[k0], 0x10000u | (z ? 1u : 0u));
            atomicAdd(&s_h1[k1], 0x10000u | (z ? 0u : 1u));
            pos0 += (xs0[j] > 0.25f) ? 1u : 0u;
            pos1 += (xs1[j] > 0.25f) ? 1u : 0u;
        }
    };

    // depth-1 prefetch, fully static (no runtime-indexed register arrays)
    Batch c0 = load(0);
    Batch c1 = load(1);      // in flight while proc(c0) runs
    proc(c0);
    Batch c2 = load(2);
    proc(c1);
    Batch c3 = load(3);
    proc(c2);
    proc(c3);

    for (int off = 32; off; off >>= 1) {
        pos0 += __shfl_down(pos0, off);
        pos1 += __shfl_down(pos1, off);
    }
    if ((tid & 63) == 0) { s_posr[tid>>6][0] = pos0; s_posr[tid>>6][1] = pos1; }
    __syncthreads();                       // also completes LDS hist atomics

    if (tid == 0) {
        unsigned q0 = 0, q1 = 0;
        #pragma unroll
        for (int w = 0; w < HT/64; ++w) { q0 += s_posr[w][0]; q1 += s_posr[w][1]; }
        g_pos[nb*CCH + 0] = q0; g_pos[nb*CCH + 1] = q1;
    }
    // one partial u32 per (ch,bucket) per block; HT == 2*NB -> one store each
    g_part[(size_t)nb*(CCH*NB) + tid] = (tid < NB) ? s_h0[tid] : s_h1[tid - NB];
}

// Kernel 2: one block per row (n,c). Thread tid owns scan position tid
// (bucket NB-1-tid): merge the BPI block-partials in registers, wave-shuffle
// u64 scan, accumulate d_mid * (iou_incl - iou_excl) in double.
// Last block (ticket) reduces the 64 rows to the final scalar.
__global__ __launch_bounds__(ST) void scan_kernel(
        const unsigned* __restrict__ g_part, const unsigned* __restrict__ g_pos,
        float* __restrict__ g_row, float* __restrict__ g_valid,
        unsigned* __restrict__ g_ticket, float* __restrict__ out)
{
    __shared__ unsigned long long s_wsum[ST/64];
    __shared__ double   s_red[ST/64];
    __shared__ unsigned s_flag;

    const int r = blockIdx.x;
    const int n = r / CCH, c = r % CCH;
    const int tid = threadIdx.x, lane = tid & 63, wv = tid >> 6;

    const int bk = NB-1 - tid;             // descending distance, position=tid
    unsigned lc = 0, lo = 0;
    #pragma unroll
    for (int b = 0; b < BPI; ++b) {
        const unsigned v = g_part[(size_t)(n*BPI + b)*(CCH*NB) + c*NB + bk];
        lc += v >> 16; lo += v & 0xffffu;
    }

    // intra-wave inclusive scan of packed (cnt<<32 | ones)
    const unsigned long long v =
        ((unsigned long long)lc << 32) | (unsigned long long)lo;
    unsigned long long s = v;
    #pragma unroll
    for (int off = 1; off < 64; off <<= 1) {
        const unsigned long long t = __shfl_up(s, off, 64);
        if (lane >= off) s += t;
    }
    if (lane == 63) s_wsum[wv] = s;
    __syncthreads();
    unsigned long long woff = 0, tot = 0;
    #pragma unroll
    for (int w = 0; w < ST/64; ++w) {
        const unsigned long long u = s_wsum[w];
        tot += u;
        if (w < wv) woff += u;
    }
    const unsigned long long excl = s + woff - v;
    const unsigned msum = (unsigned)(tot & 0xffffffffu);
    const unsigned k  = (unsigned)(excl >> 32);
    const unsigned cs = (unsigned)(excl & 0xffffffffu);

    double acc = 0.0;
    if (lc) {
        const double dmsum = (double)msum;
        const double ip  = iou_f(dmsum, k, cs);
        const double in_ = iou_f(dmsum, k + lc, cs + lo);
        acc = (((double)bk + 0.5) * (1.0/(double)NB)) * (in_ - ip);
    }
    for (int off = 32; off; off >>= 1) acc += __shfl_down(acc, off);
    if (lane == 0) s_red[wv] = acc;
    __syncthreads();
    if (tid == 0) {
        double t = 0.0;
        #pragma unroll
        for (int w = 0; w < ST/64; ++w) t += s_red[w];
        unsigned pos = 0;
        for (int b = 0; b < BPI; ++b) pos += g_pos[(n*BPI + b)*CCH + c];
        const bool valid = !(msum == 0u && pos == 0u);
        const double W[CCH] = {1.428, 40.097};
        g_row[r]   = valid ? (float)(t * W[c]) : 0.f;
        g_valid[r] = valid ? 1.f : 0.f;
        __threadfence();                   // publish row result device-wide
        s_flag = atomicAdd(g_ticket, 1u);  // device-scope by default
    }
    __syncthreads();

    if (s_flag == RR - 1) {                // last block reduces all rows
        __threadfence();
        if (tid < 64) {
            const volatile float* vr = g_row;
            const volatile float* vv = g_valid;
            double t  = (tid < RR) ? (double)vr[tid] : 0.0;
            double vl = (tid < RR) ? (double)vv[tid] : 0.0;
            for (int off = 32; off; off >>= 1) {
                t  += __shfl_down(t, off);
                vl += __shfl_down(vl, off);
            }
            if (tid == 0) out[0] = (float)(t / (double)NN / vl);
        }
    }
}

extern "C" void kernel_launch(void* const* d_in, const int* in_sizes, int n_in,
                              void* d_out, int out_size, void* d_ws, size_t ws_size,
                              hipStream_t stream) {
    const float* x   = (const float*)d_in[0];
    const int*   tgt = (const int*)d_in[1];
    float* out = (float*)d_out;

    // workspace (~1.1 MB): every word written before read -> no memset
    const size_t SZP = (size_t)GRID * CCH * NB;          // partials (u32)
    unsigned* g_part  = (unsigned*)d_ws;
    unsigned* g_pos   = g_part + SZP;                    // GRID*2 u32
    float*    g_row   = (float*)(g_pos + GRID*CCH);      // RR floats
    float*    g_valid = g_row + RR;                      // RR floats
    unsigned* g_ticket = (unsigned*)(g_valid + RR);      // 1 u32

    hist_kernel<<<GRID, HT, 0, stream>>>(x, tgt, g_part, g_pos, g_ticket);
    scan_kernel<<<RR, ST, 0, stream>>>(g_part, g_pos, g_row, g_valid, g_ticket, out);
}